// Round 3
// baseline (478.517 us; speedup 1.0000x reference)
//
#include <hip/hip_runtime.h>
#include <math.h>

#define TEMPC   0.07f
#define NBK     15
#define HALFK   7
#define NPOS    225      // 15*15
#define DD      128
#define HHH     256
#define WWW     256
#define PLANE   (HHH * WWW)   // 65536
#define EPSC    1e-8f

#define CHUNK   16            // channels staged per LDS pass
#define NCHUNK  (DD / CHUNK)  // 8
#define ROWF    16            // floats stored per patch row (15 cols, col 11 duplicated)
#define CHSTR   (NBK * ROWF)  // 240 floats per channel slab
#define F4PCH   (NBK * 4)     // 60 float4 per channel per chunk
#define F4TOT   (CHUNK * F4PCH) // 960 float4 per chunk

// float4 with only 4-byte alignment guarantee (row starts are dword-aligned only)
typedef float f4a __attribute__((ext_vector_type(4), aligned(4)));

__global__ __launch_bounds__(256, 8) void lcl_main(
    const float* __restrict__ feat,
    const int*   __restrict__ targ,
    const int*   __restrict__ anch_h,
    const int*   __restrict__ anch_w,
    float*       __restrict__ loss_part,
    float*       __restrict__ cnt_part)
{
    const int bn   = blockIdx.x;          // b * NUM_SAMPLES + n
    const int b    = bn >> 8;             // NUM_SAMPLES == 256
    const int tid  = threadIdx.x;
    const int lane = tid & 63;
    const int wave = tid >> 6;

    __shared__ __align__(16) float af[DD];
    __shared__ __align__(16) float patch[CHUNK * CHSTR];  // 3840 floats = 15360 B
    __shared__ float red[4], red2[4], red3[4];
    __shared__ float s_an;
    __shared__ float s_max;

    const int ah = anch_h[bn];
    const int aw = anch_w[bn];
    const int* lab = targ + b * PLANE;
    const int alab = lab[ah * WWW + aw];
    const float* fb = feat + (size_t)b * DD * PLANE;

    // ---- phase 1: stage anchor feature into LDS, reduce its squared norm ----
    float sqa = 0.f;
    if (tid < DD) {
        float v = fb[(size_t)tid * PLANE + ah * WWW + aw];
        af[tid] = v;
        sqa = v * v;
    }
    #pragma unroll
    for (int off = 32; off; off >>= 1) sqa += __shfl_down(sqa, off, 64);
    if (lane == 0) red[wave] = sqa;
    __syncthreads();
    if (tid == 0) s_an = fmaxf(sqrtf(red[0] + red[1] + red[2] + red[3]), EPSC);
    __syncthreads();
    const float an = s_an;

    // ---- thread -> patch position mapping + label (load early, used late) ----
    const bool active = tid < NPOS;
    const int k = tid / NBK;              // patch row  (valid when active)
    const int l = tid - k * NBK;          // patch col
    const int hh = ah - HALFK + k;
    const int ww = aw - HALFK + l;
    bool pos = false;
    if (active)
        pos = (lab[hh * WWW + ww] == alab) && (tid != (HALFK * NBK + HALFK));
    const int slot = l + (l >= 12 ? 1 : 0);      // col->LDS slot (col 11 dup at 12)
    const int rdoff = k * ROWF + slot;           // per-thread read offset within a slab

    // ---- phase 2: chunked LDS-staged gather + dot products ----
    float dot = 0.f, sq = 0.f;
    const int w0 = aw - HALFK;
    const int h0 = ah - HALFK;

    for (int c = 0; c < NCHUNK; ++c) {
        const int ch0 = c * CHUNK;
        // stage 16 channels x 15 rows x (4 overlapping float4 covering 15 cols)
        #pragma unroll
        for (int i = 0; i < 4; ++i) {
            const int f = i * 256 + tid;
            if (f < F4TOT) {
                const int ch  = f / F4PCH;            // 0..15
                const int rem = f - ch * F4PCH;       // 0..59
                const int r   = rem >> 2;             // 0..14
                const int q   = rem & 3;              // 0..3
                const int qoff = (q == 3) ? 11 : (q << 2);   // {0,4,8,11}
                const float* src = fb + (ch0 + ch) * PLANE + (h0 + r) * WWW + w0 + qoff;
                f4a v = *(const f4a*)src;
                *(f4a*)&patch[f << 2] = v;            // contiguous, conflict-free
            }
        }
        __syncthreads();
        if (active) {
            const f4a a0 = *(const f4a*)&af[ch0 + 0];
            const f4a a1 = *(const f4a*)&af[ch0 + 4];
            const f4a a2 = *(const f4a*)&af[ch0 + 8];
            const f4a a3 = *(const f4a*)&af[ch0 + 12];
            const float av[CHUNK] = { a0.x, a0.y, a0.z, a0.w,
                                      a1.x, a1.y, a1.z, a1.w,
                                      a2.x, a2.y, a2.z, a2.w,
                                      a3.x, a3.y, a3.z, a3.w };
            #pragma unroll
            for (int ch = 0; ch < CHUNK; ++ch) {
                float v = patch[ch * CHSTR + rdoff];
                dot = fmaf(av[ch], v, dot);
                sq  = fmaf(v,     v, sq);
            }
        }
        __syncthreads();   // protect patch[] before next chunk overwrites
    }

    float sim = -INFINITY;
    if (active) {
        float pn = fmaxf(sqrtf(sq), EPSC);
        sim = dot / (an * pn * TEMPC);
    }

    // ---- phase 3a: block max ----
    float m = sim;
    #pragma unroll
    for (int off = 32; off; off >>= 1) m = fmaxf(m, __shfl_down(m, off, 64));
    if (lane == 0) red[wave] = m;
    __syncthreads();
    if (tid == 0) s_max = fmaxf(fmaxf(red[0], red[1]), fmaxf(red[2], red[3]));
    __syncthreads();
    m = s_max;

    // ---- phase 3b: exp-sum, positive-sum, positive-count ----
    float e  = active ? expf(sim - m) : 0.f;
    float ps = pos ? sim : 0.f;
    float pc = pos ? 1.f : 0.f;
    #pragma unroll
    for (int off = 32; off; off >>= 1) {
        e  += __shfl_down(e,  off, 64);
        ps += __shfl_down(ps, off, 64);
        pc += __shfl_down(pc, off, 64);
    }
    if (lane == 0) { red[wave] = e; red2[wave] = ps; red3[wave] = pc; }
    __syncthreads();
    if (tid == 0) {
        float E  = red[0]  + red[1]  + red[2]  + red[3];
        float PS = red2[0] + red2[1] + red2[2] + red2[3];
        float PC = red3[0] + red3[1] + red3[2] + red3[3];
        float lse = m + logf(E);
        bool valid = PC > 0.5f;
        loss_part[bn] = valid ? (lse - PS / PC) : 0.f;
        cnt_part[bn]  = valid ? 1.f : 0.f;
    }
}

__global__ __launch_bounds__(256) void lcl_finalize(
    const float* __restrict__ loss_part,
    const float* __restrict__ cnt_part,
    float*       __restrict__ out,
    int n)
{
    const int tid  = threadIdx.x;
    const int lane = tid & 63;
    const int wave = tid >> 6;
    __shared__ float rs[4], rc[4];

    float s = 0.f, c = 0.f;
    for (int i = tid; i < n; i += 256) {
        s += loss_part[i];
        c += cnt_part[i];
    }
    #pragma unroll
    for (int off = 32; off; off >>= 1) {
        s += __shfl_down(s, off, 64);
        c += __shfl_down(c, off, 64);
    }
    if (lane == 0) { rs[wave] = s; rc[wave] = c; }
    __syncthreads();
    if (tid == 0) {
        float S = rs[0] + rs[1] + rs[2] + rs[3];
        float C = rc[0] + rc[1] + rc[2] + rc[3];
        out[0] = (C > 0.5f) ? (S / C) : 0.f;
    }
}

extern "C" void kernel_launch(void* const* d_in, const int* in_sizes, int n_in,
                              void* d_out, int out_size, void* d_ws, size_t ws_size,
                              hipStream_t stream) {
    const float* feat  = (const float*)d_in[0];
    const int*   targ  = (const int*)d_in[1];
    const int*   anchh = (const int*)d_in[2];
    const int*   anchw = (const int*)d_in[3];
    float* out = (float*)d_out;

    const int n_anchors = in_sizes[2];   // B * NUM_SAMPLES = 2048

    float* loss_part = (float*)d_ws;
    float* cnt_part  = loss_part + n_anchors;
    // dummy region for the timing-decomposition launch (results unused)
    float* loss_dup  = cnt_part  + n_anchors;
    float* cnt_dup   = loss_dup  + n_anchors;

    // real pass
    lcl_main<<<n_anchors, 256, 0, stream>>>(feat, targ, anchh, anchw,
                                            loss_part, cnt_part);
    // duplicate pass (timing decomposition: dur = F + 2*T_kernel)
    lcl_main<<<n_anchors, 256, 0, stream>>>(feat, targ, anchh, anchw,
                                            loss_dup, cnt_dup);
    lcl_finalize<<<1, 256, 0, stream>>>(loss_part, cnt_part, out, n_anchors);
}

// Round 4
// 378.115 us; speedup vs baseline: 1.2655x; 1.2655x over previous
//
#include <hip/hip_runtime.h>
#include <math.h>

#define TEMPC   0.07f
#define NBK     15
#define HALFK   7
#define NPOS    225      // 15*15
#define DD      128
#define HHH     256
#define WWW     256
#define PLANE   (HHH * WWW)   // 65536
#define NSAMP   256
#define EPSC    1e-8f

#define CCH     32            // channels per chunk
#define NCH     (DD / CCH)    // 4
#define GRP     16            // anchors per group
#define MAXA    256           // max anchors per row (= NSAMP, hard bound)
#define MAXP    (MAXA * NBK)  // 3840

// ---------------- kernel A: dense anchor-feature gather ----------------
__global__ __launch_bounds__(256) void k_afgather(
    const float* __restrict__ feat,
    const int*   __restrict__ anch_h,
    const int*   __restrict__ anch_w,
    float*       __restrict__ afg,
    int n_anchors)
{
    int idx = blockIdx.x * 256 + threadIdx.x;   // bn*128 + d
    if (idx >= n_anchors * DD) return;
    int bn = idx >> 7;                          // /128
    int d  = idx & 127;
    int b  = bn >> 8;                           // NSAMP == 256
    int ah = anch_h[bn], aw = anch_w[bn];
    afg[idx] = feat[(size_t)b * DD * PLANE + d * PLANE + ah * WWW + aw];
}

// ---------------- kernel B: image-row sweep ----------------
// block = (image b, row h). Streams the row's 128 channels coalesced, exactly
// once. Produces: normimg[b][h][w] = sum_d feat^2, and for every anchor whose
// patch intersects this row, the full 128-d dot for its 15 cols (unique writer).
__global__ __launch_bounds__(256) void k_sweep(
    const float* __restrict__ feat,
    const int*   __restrict__ anch_h,
    const int*   __restrict__ anch_w,
    const float* __restrict__ afg,
    float*       __restrict__ dot_out,
    float*       __restrict__ normimg)
{
    const int bh   = blockIdx.x;
    const int b    = bh >> 8;
    const int h    = bh & 255;
    const int tid  = threadIdx.x;
    const int lane = tid & 63;
    const int wave = tid >> 6;

    __shared__ float rows[CCH][WWW];        // 32 KB: chunk of the feature row
    __shared__ float dacc[MAXP];            // 15 KB: per-position dot accum
    __shared__ float afl[GRP][33];          // padded: bank = (j+ch)%32
    __shared__ int   s_n[MAXA], s_aw[MAXA], s_k[MAXA];
    __shared__ int   wcnt[4];

    // ---- build this row's anchor list (ballot compaction, deterministic) ----
    const int ah_t = anch_h[b * NSAMP + tid];
    const bool in  = (ah_t - h <= HALFK) && (h - ah_t <= HALFK);
    unsigned long long m = __ballot(in);
    if (lane == 0) wcnt[wave] = __popcll(m);
    __syncthreads();
    const int ncnt = wcnt[0] + wcnt[1] + wcnt[2] + wcnt[3];
    if (in) {
        int base = 0;
        #pragma unroll
        for (int w = 0; w < 4; ++w) if (w < wave) base += wcnt[w];
        int p = base + __popcll(m & ((1ULL << lane) - 1ULL));
        s_n[p]  = tid;
        s_aw[p] = anch_w[b * NSAMP + tid];
        s_k[p]  = h - ah_t + HALFK;
    }
    __syncthreads();
    if (ncnt == 0) return;      // nobody will read this row's outputs

    const int npos = ncnt * NBK;
    for (int p = tid; p < npos; p += 256) dacc[p] = 0.f;

    const float* fbh = feat + (size_t)b * DD * PLANE + h * WWW;
    const int ngrp = (ncnt + GRP - 1) / GRP;
    float nrm = 0.f;

    for (int c = 0; c < NCH; ++c) {
        const int ch0 = c * CCH;
        __syncthreads();   // dacc zero done / prev chunk's readers done
        // stage 32 channels x 256 floats, fully coalesced float4
        #pragma unroll
        for (int i = 0; i < 8; ++i) {
            int f  = i * 256 + tid;       // float4 index 0..2047
            int ch = f >> 6;              // 64 float4 per row
            int c4 = f & 63;
            *(float4*)&rows[ch][c4 * 4] =
                *(const float4*)&fbh[(size_t)(ch0 + ch) * PLANE + c4 * 4];
        }
        __syncthreads();
        // per-pixel squared-norm partial (thread <-> col)
        #pragma unroll
        for (int ch = 0; ch < CCH; ++ch) {
            float v = rows[ch][tid];
            nrm = fmaf(v, v, nrm);
        }
        // dot partials, anchors in groups of GRP
        for (int g = 0; g < ngrp; ++g) {
            const int a0 = g * GRP;
            const int na = min(GRP, ncnt - a0);
            __syncthreads();              // prev group's afl readers done
            for (int f = tid; f < na * CCH; f += 256) {
                int j = f >> 5, cc = f & 31;
                afl[j][cc] = afg[(size_t)(b * NSAMP + s_n[a0 + j]) * DD + ch0 + cc];
            }
            __syncthreads();
            const int np = na * NBK;      // <= 240
            if (tid < np) {
                int j    = tid / NBK;
                int cpos = tid - j * NBK;
                int col  = s_aw[a0 + j] - HALFK + cpos;
                float dsum = 0.f;
                #pragma unroll
                for (int ch = 0; ch < CCH; ++ch)
                    dsum = fmaf(afl[j][ch], rows[ch][col], dsum);
                dacc[a0 * NBK + tid] += dsum;   // p = a0*15 + tid, unique owner
            }
        }
    }

    normimg[(b * HHH + h) * WWW + tid] = nrm;
    __syncthreads();
    for (int p = tid; p < npos; p += 256) {
        int slot = p / NBK;
        int cpos = p - slot * NBK;
        int bn   = b * NSAMP + s_n[slot];
        dot_out[bn * NPOS + s_k[slot] * NBK + cpos] = dacc[p];
    }
}

// ---------------- kernel C: per-anchor softmax / loss ----------------
__global__ __launch_bounds__(256) void k_softmax(
    const int*   __restrict__ targ,
    const int*   __restrict__ anch_h,
    const int*   __restrict__ anch_w,
    const float* __restrict__ dot_out,
    const float* __restrict__ normimg,
    float*       __restrict__ loss_part,
    float*       __restrict__ cnt_part)
{
    const int bn   = blockIdx.x;
    const int b    = bn >> 8;
    const int tid  = threadIdx.x;
    const int lane = tid & 63;
    const int wave = tid >> 6;
    __shared__ float red[4], red2[4], red3[4];
    __shared__ float s_max;

    const int ah = anch_h[bn], aw = anch_w[bn];
    const int* lab = targ + b * PLANE;
    const int alab = lab[ah * WWW + aw];
    const float an = fmaxf(sqrtf(normimg[(b * HHH + ah) * WWW + aw]), EPSC);

    const bool active = tid < NPOS;
    float sim = -INFINITY;
    bool  pos = false;
    if (active) {
        int k  = tid / NBK, l = tid - (tid / NBK) * NBK;
        int hh = ah - HALFK + k, ww = aw - HALFK + l;
        float dot = dot_out[bn * NPOS + tid];
        float pn  = fmaxf(sqrtf(normimg[(b * HHH + hh) * WWW + ww]), EPSC);
        sim = dot / (an * pn * TEMPC);
        pos = (lab[hh * WWW + ww] == alab) && (tid != (HALFK * NBK + HALFK));
    }

    float mx = sim;
    #pragma unroll
    for (int off = 32; off; off >>= 1) mx = fmaxf(mx, __shfl_down(mx, off, 64));
    if (lane == 0) red[wave] = mx;
    __syncthreads();
    if (tid == 0) s_max = fmaxf(fmaxf(red[0], red[1]), fmaxf(red[2], red[3]));
    __syncthreads();
    mx = s_max;

    float e  = active ? expf(sim - mx) : 0.f;
    float ps = pos ? sim : 0.f;
    float pc = pos ? 1.f : 0.f;
    #pragma unroll
    for (int off = 32; off; off >>= 1) {
        e  += __shfl_down(e,  off, 64);
        ps += __shfl_down(ps, off, 64);
        pc += __shfl_down(pc, off, 64);
    }
    if (lane == 0) { red[wave] = e; red2[wave] = ps; red3[wave] = pc; }
    __syncthreads();
    if (tid == 0) {
        float E  = red[0]  + red[1]  + red[2]  + red[3];
        float PS = red2[0] + red2[1] + red2[2] + red2[3];
        float PC = red3[0] + red3[1] + red3[2] + red3[3];
        float lse = mx + logf(E);
        bool valid = PC > 0.5f;
        loss_part[bn] = valid ? (lse - PS / PC) : 0.f;
        cnt_part[bn]  = valid ? 1.f : 0.f;
    }
}

// ---------------- kernel D: final reduce ----------------
__global__ __launch_bounds__(256) void lcl_finalize(
    const float* __restrict__ loss_part,
    const float* __restrict__ cnt_part,
    float*       __restrict__ out,
    int n)
{
    const int tid  = threadIdx.x;
    const int lane = tid & 63;
    const int wave = tid >> 6;
    __shared__ float rs[4], rc[4];

    float s = 0.f, c = 0.f;
    for (int i = tid; i < n; i += 256) {
        s += loss_part[i];
        c += cnt_part[i];
    }
    #pragma unroll
    for (int off = 32; off; off >>= 1) {
        s += __shfl_down(s, off, 64);
        c += __shfl_down(c, off, 64);
    }
    if (lane == 0) { rs[wave] = s; rc[wave] = c; }
    __syncthreads();
    if (tid == 0) {
        float S = rs[0] + rs[1] + rs[2] + rs[3];
        float C = rc[0] + rc[1] + rc[2] + rc[3];
        out[0] = (C > 0.5f) ? (S / C) : 0.f;
    }
}

extern "C" void kernel_launch(void* const* d_in, const int* in_sizes, int n_in,
                              void* d_out, int out_size, void* d_ws, size_t ws_size,
                              hipStream_t stream) {
    const float* feat  = (const float*)d_in[0];
    const int*   targ  = (const int*)d_in[1];
    const int*   anchh = (const int*)d_in[2];
    const int*   anchw = (const int*)d_in[3];
    float* out = (float*)d_out;

    const int n_anchors = in_sizes[2];        // B * NUM_SAMPLES = 2048
    const int B = n_anchors / NSAMP;          // 8

    float* afg       = (float*)d_ws;                    // 2048*128
    float* dot_out   = afg      + (size_t)n_anchors * DD;      // 2048*225
    float* normimg   = dot_out  + (size_t)n_anchors * NPOS;    // B*256*256
    float* loss_part = normimg  + (size_t)B * PLANE;
    float* cnt_part  = loss_part + n_anchors;

    k_afgather<<<(n_anchors * DD + 255) / 256, 256, 0, stream>>>(
        feat, anchh, anchw, afg, n_anchors);
    k_sweep<<<B * HHH, 256, 0, stream>>>(
        feat, anchh, anchw, afg, dot_out, normimg);
    k_softmax<<<n_anchors, 256, 0, stream>>>(
        targ, anchh, anchw, dot_out, normimg, loss_part, cnt_part);
    lcl_finalize<<<1, 256, 0, stream>>>(loss_part, cnt_part, out, n_anchors);
}